// Round 10
// baseline (174.230 us; speedup 1.0000x reference)
//
#include <hip/hip_runtime.h>

#define H 384
#define W 384
#define HWSZ (H * W)
#define NB 16
#define ND 2048
#define DD 256

// workspace byte offsets (all 256-aligned)
#define OFF_RESP  256
#define OFF_CVAL  9437440
#define OFF_CPOS  9584896
#define OFF_DESCB 9732352     // fp8 descriptors: 16*2048*256 = 8.4 MB
#define OFF_INV   26509568
#define OFF_PSOFT 26640640    // 576 floats
#define OFF_PGEMM 26643200    // 2176 floats
#define OFF_PCORN 26652160    // 16 floats

__device__ __forceinline__ int clampi(int v) { return v < 0 ? 0 : (v > 383 ? 383 : v); }
__device__ __forceinline__ int refl(int v) { return v < 0 ? -v : (v >= 384 ? 766 - v : v); }

// fp32 -> OCP e4m3fn with RNE. Layout: [s:1][eeee:4][mmm:3] -> s<<7 | e<<3 | m.
__device__ __forceinline__ unsigned f2e4m3(float x) {
  float a = fabsf(x);
  unsigned s = (__float_as_uint(x) >> 31) << 7;
  if (a >= 448.f) return s | 0x7E;
  if (a < 0.015625f) {
    int m = (int)rintf(a * 512.f);
    return s | (unsigned)m;
  }
  unsigned u = __float_as_uint(a);
  u += 0x7FFFF + ((u >> 20) & 1);
  unsigned e = (u >> 23) - 120;
  unsigned m = (u >> 20) & 7;
  return s | (e << 3) | m;
}

typedef float f32x4 __attribute__((ext_vector_type(4)));

__device__ __forceinline__ void load_lds16(const void* g, void* l) {
  __builtin_amdgcn_global_load_lds((const __attribute__((address_space(1))) void*)g,
                                   (__attribute__((address_space(3))) void*)l, 16, 0, 0);
}

// ---------------------------------------------------------------------------
// STAGE 1: resp (0..2303) || prep_desc (2304..10495) || softplus (10496..11071).
// resp stencils vectorized: b128 LDS reads/writes in gauss passes (R7 profile:
// ~235 scalar ds_read_b32/thread was the bottleneck). LDS re-padded for 16B
// alignment; gl and t share a union buffer (lifetimes barrier-separated).
// (256,4) launch bounds: 128-VGPR budget -> no spill (R8's spill root cause
// was the default 8-wave target's 64-VGPR cap).
// ---------------------------------------------------------------------------
__global__ __launch_bounds__(256, 4) void stage1_kernel(const float* __restrict__ imgs,
                                                        float* __restrict__ resp,
                                                        const float* __restrict__ desc,
                                                        unsigned char* __restrict__ descF8,
                                                        float* __restrict__ invn,
                                                        const float4* __restrict__ sd4,
                                                        float* __restrict__ psoft) {
  __shared__ float4 pbuf4[1140];   // p0/p1/p2: 3 x [38][40] floats = 4560 floats
  __shared__ float4 ubuf4[1026];   // union: gl [40][40] (phases 0-1) / t0..t2 [38][36] (2-3)
  float* p0 = (float*)pbuf4;
  float* p1 = p0 + 1520;
  float* p2 = p0 + 3040;
  float* glf = (float*)ubuf4;
  float* t0 = (float*)ubuf4;
  float* t1 = t0 + 1368;
  float* t2 = t0 + 2736;

  if (blockIdx.x >= 10496) {
    // ---- softplus partial sums ----
    float* r4s = (float*)pbuf4;
    int sb = blockIdx.x - 10496;
    float s = 0.f;
    int base = sb * 256 + threadIdx.x;
#pragma unroll
    for (int it = 0; it < 4; it++) {
      float4 v = sd4[base + it * 147456];
      s += fmaxf(v.x, 0.f) + log1pf(expf(-fabsf(v.x))) +
           fmaxf(v.y, 0.f) + log1pf(expf(-fabsf(v.y))) +
           fmaxf(v.z, 0.f) + log1pf(expf(-fabsf(v.z))) +
           fmaxf(v.w, 0.f) + log1pf(expf(-fabsf(v.w)));
    }
    for (int off = 32; off; off >>= 1) s += __shfl_down(s, off, 64);
    if ((threadIdx.x & 63) == 0) r4s[threadIdx.x >> 6] = s;
    __syncthreads();
    if (threadIdx.x == 0) psoft[sb] = r4s[0] + r4s[1] + r4s[2] + r4s[3];
    return;
  }

  if (blockIdx.x >= 2304) {
    // ---- prep_desc: fp32 -> fp8 e4m3 + per-row inverse norm ----
    int wave = threadIdx.x >> 6, lane = threadIdx.x & 63;
    int row = (blockIdx.x - 2304) * 4 + wave;
    const float4* src = (const float4*)(desc + (size_t)row * DD);
    float4 v = src[lane];
    unsigned pk = f2e4m3(v.x) | (f2e4m3(v.y) << 8) | (f2e4m3(v.z) << 16) | (f2e4m3(v.w) << 24);
    ((unsigned*)(descF8 + (size_t)row * DD))[lane] = pk;
    float ss = v.x * v.x + v.y * v.y + v.z * v.z + v.w * v.w;
    for (int off = 32; off; off >>= 1) ss += __shfl_down(ss, off, 64);
    if (lane == 0) invn[row] = 1.f / fmaxf(sqrtf(ss), 1e-4f);
    return;
  }

  // ---- resp: gray -> sobel(edge) -> products -> 7x7 gauss(reflect) -> GFTT ----
  const float GW[7] = {0.0044330482f, 0.0540055826f, 0.2420362294f, 0.3990502160f,
                       0.2420362294f, 0.0540055826f, 0.0044330482f};
  int bid = blockIdx.x;
  int b = bid / 144;
  int t = bid % 144;
  int Y0 = (t / 12) * 32, X0 = (t % 12) * 32;
  const float* ib = imgs + (size_t)b * 3 * HWSZ;

  // phase 0: gray tile [40][40] with 4-halo, edge-clamped
  for (int i = threadIdx.x; i < 1600; i += 256) {
    int r = i / 40, c = i % 40;
    int gy = clampi(Y0 - 4 + r), gx = clampi(X0 - 4 + c);
    const float* p = ib + gy * W + gx;
    glf[i] = 0.299f * p[0] + 0.587f * p[HWSZ] + 0.114f * p[2 * HWSZ];
  }
  __syncthreads();

  bool interior = (X0 >= 32 && X0 <= 320 && Y0 >= 32 && Y0 <= 320);

  // phase 1: structure-tensor products -> p[38][40]
  if (interior) {
    // interior: refl/clamp identity; vectorized 4-wide, c-major lane mapping
    for (int g = threadIdx.x; g < 380; g += 256) {
      int r = g / 10, c0 = (g % 10) * 4;
      const float* row = glf + r * 40 + c0;
      float4 A0 = *(const float4*)(row);
      float2 B0 = *(const float2*)(row + 4);
      float4 A1 = *(const float4*)(row + 40);
      float2 B1 = *(const float2*)(row + 44);
      float4 A2 = *(const float4*)(row + 80);
      float2 B2 = *(const float2*)(row + 84);
      float w0[6] = {A0.x, A0.y, A0.z, A0.w, B0.x, B0.y};
      float w1[6] = {A1.x, A1.y, A1.z, A1.w, B1.x, B1.y};
      float w2[6] = {A2.x, A2.y, A2.z, A2.w, B2.x, B2.y};
#pragma unroll
      for (int k = 0; k < 4; k++) {
        int cc = c0 + k;
        if (cc < 38) {
          float a = w0[k], bb = w0[k + 1], cv = w0[k + 2];
          float d = w1[k], e = w1[k + 2];
          float f = w2[k], gg = w2[k + 1], h = w2[k + 2];
          float dx = 0.125f * ((cv - a) + 2.f * (e - d) + (h - f));
          float dy = 0.125f * ((f - a) + 2.f * (gg - bb) + (h - cv));
          p0[r * 40 + cc] = dx * dx;
          p1[r * 40 + cc] = dy * dy;
          p2[r * 40 + cc] = dx * dy;
        }
      }
    }
  } else {
    for (int i = threadIdx.x; i < 1444; i += 256) {
      int r = i / 38, c = i % 38;
      int py = refl(Y0 - 3 + r), px = refl(X0 - 3 + c);
      int ym = clampi(py - 1) - (Y0 - 4), y0 = py - (Y0 - 4), yp = clampi(py + 1) - (Y0 - 4);
      int xm = clampi(px - 1) - (X0 - 4), x0 = px - (X0 - 4), xp = clampi(px + 1) - (X0 - 4);
      float a = glf[ym * 40 + xm], bb = glf[ym * 40 + x0], cc = glf[ym * 40 + xp];
      float d = glf[y0 * 40 + xm], e = glf[y0 * 40 + xp];
      float f = glf[yp * 40 + xm], g = glf[yp * 40 + x0], h = glf[yp * 40 + xp];
      float dx = 0.125f * ((cc - a) + 2.f * (e - d) + (h - f));
      float dy = 0.125f * ((f - a) + 2.f * (g - bb) + (h - cc));
      p0[r * 40 + c] = dx * dx;
      p1[r * 40 + c] = dy * dy;
      p2[r * 40 + c] = dx * dy;
    }
  }
  __syncthreads();

  // phase 2: horizontal gauss, vectorized: 3x b128 reads + 1x b128 write per
  // array per 4 outputs. (gl is dead; t overlays it.)
  for (int g = threadIdx.x; g < 304; g += 256) {
    int r = g >> 3, c0 = (g & 7) * 4;
    {
      const float* pr = p0 + r * 40 + c0;
      float4 A = *(const float4*)(pr), B = *(const float4*)(pr + 4), C = *(const float4*)(pr + 8);
      float w[12] = {A.x, A.y, A.z, A.w, B.x, B.y, B.z, B.w, C.x, C.y, C.z, C.w};
      float s[4];
#pragma unroll
      for (int k = 0; k < 4; k++) {
        float sv = 0.f;
#pragma unroll
        for (int j = 0; j < 7; j++) sv += GW[j] * w[k + j];
        s[k] = sv;
      }
      *(float4*)(t0 + r * 36 + c0) = (float4){s[0], s[1], s[2], s[3]};
    }
    {
      const float* pr = p1 + r * 40 + c0;
      float4 A = *(const float4*)(pr), B = *(const float4*)(pr + 4), C = *(const float4*)(pr + 8);
      float w[12] = {A.x, A.y, A.z, A.w, B.x, B.y, B.z, B.w, C.x, C.y, C.z, C.w};
      float s[4];
#pragma unroll
      for (int k = 0; k < 4; k++) {
        float sv = 0.f;
#pragma unroll
        for (int j = 0; j < 7; j++) sv += GW[j] * w[k + j];
        s[k] = sv;
      }
      *(float4*)(t1 + r * 36 + c0) = (float4){s[0], s[1], s[2], s[3]};
    }
    {
      const float* pr = p2 + r * 40 + c0;
      float4 A = *(const float4*)(pr), B = *(const float4*)(pr + 4), C = *(const float4*)(pr + 8);
      float w[12] = {A.x, A.y, A.z, A.w, B.x, B.y, B.z, B.w, C.x, C.y, C.z, C.w};
      float s[4];
#pragma unroll
      for (int k = 0; k < 4; k++) {
        float sv = 0.f;
#pragma unroll
        for (int j = 0; j < 7; j++) sv += GW[j] * w[k + j];
        s[k] = sv;
      }
      *(float4*)(t2 + r * 36 + c0) = (float4){s[0], s[1], s[2], s[3]};
    }
  }
  __syncthreads();

  // phase 3: vertical gauss + GFTT, 4 rows/thread (exactly 256 groups),
  // scalar reads are conflict-free (t row stride 36 == 4 mod 32 banks).
  {
    int r0 = (threadIdx.x >> 5) * 4, c = threadIdx.x & 31;
    float s0[4], s1[4], s2[4];
    {
      float a[10];
#pragma unroll
      for (int dr = 0; dr < 10; dr++) a[dr] = t0[(r0 + dr) * 36 + c];
#pragma unroll
      for (int k = 0; k < 4; k++) {
        float sv = 0.f;
#pragma unroll
        for (int j = 0; j < 7; j++) sv += GW[j] * a[k + j];
        s0[k] = sv;
      }
    }
    {
      float a[10];
#pragma unroll
      for (int dr = 0; dr < 10; dr++) a[dr] = t1[(r0 + dr) * 36 + c];
#pragma unroll
      for (int k = 0; k < 4; k++) {
        float sv = 0.f;
#pragma unroll
        for (int j = 0; j < 7; j++) sv += GW[j] * a[k + j];
        s1[k] = sv;
      }
    }
    {
      float a[10];
#pragma unroll
      for (int dr = 0; dr < 10; dr++) a[dr] = t2[(r0 + dr) * 36 + c];
#pragma unroll
      for (int k = 0; k < 4; k++) {
        float sv = 0.f;
#pragma unroll
        for (int j = 0; j < 7; j++) sv += GW[j] * a[k + j];
        s2[k] = sv;
      }
    }
#pragma unroll
    for (int k = 0; k < 4; k++) {
      float tr = s0[k] + s1[k];
      float det = s0[k] * s1[k] - s2[k] * s2[k];
      float disc = tr * tr - 4.f * det;
      float rv = 0.5f * (tr - sqrtf(fabsf(disc)));
      resp[(size_t)b * HWSZ + (Y0 + r0 + k) * W + (X0 + c)] = rv;
    }
  }
}

// ---------------------------------------------------------------------------
// STAGE 2: fp8 Gram-GEMM relu-sum (blocks 0..2175) || nms (2176..2751).
// Dynamic shared memory overlays the two branches' LDS.
// ---------------------------------------------------------------------------
__global__ __launch_bounds__(256, 4) void stage2_kernel(const unsigned char* __restrict__ descF8,
                                                        const float* __restrict__ invn,
                                                        float* __restrict__ pgemm,
                                                        const float* __restrict__ resp,
                                                        float* __restrict__ cval,
                                                        unsigned* __restrict__ cpos) {
  extern __shared__ char smem2[];

  if (blockIdx.x >= 2176) {
    // ---- 5x5 NMS (-inf border) + per-8x8-block max candidate ----
    float (*rl)[69] = (float(*)[69])smem2;
    float (*nl)[65] = (float(*)[65])(smem2 + 68 * 69 * 4);
    int bid = blockIdx.x - 2176;
    int b = bid / 36;
    int t = bid % 36;
    int Y0 = (t / 6) * 64, X0 = (t % 6) * 64;
    const float* rb = resp + (size_t)b * HWSZ;

    for (int i = threadIdx.x; i < 68 * 68; i += 256) {
      int r = i / 68, c = i % 68;
      int gy = Y0 - 2 + r, gx = X0 - 2 + c;
      float v = -INFINITY;
      if (gy >= 0 && gy < H && gx >= 0 && gx < W) v = rb[gy * W + gx];
      rl[r][c] = v;
    }
    __syncthreads();

    for (int i = threadIdx.x; i < 4096; i += 256) {
      int r = i / 64, c = i % 64;
      float m = -INFINITY;
#pragma unroll
      for (int dr = 0; dr < 5; dr++)
#pragma unroll
        for (int dc = 0; dc < 5; dc++) m = fmaxf(m, rl[r + dr][c + dc]);
      float v = rl[r + 2][c + 2];
      nl[r][c] = (v == m) ? v : 0.f;
    }
    __syncthreads();

    if (threadIdx.x < 64) {
      int bi = threadIdx.x / 8, bj = threadIdx.x % 8;
      float bv = 0.f;
      unsigned bp = 0;
      for (int rr = 0; rr < 8; rr++)
        for (int cc = 0; cc < 8; cc++) {
          float v = nl[bi * 8 + rr][bj * 8 + cc];
          if (v > bv) { bv = v; bp = (unsigned)((Y0 + bi * 8 + rr) * W + (X0 + bj * 8 + cc)); }
        }
      int ci = b * 2304 + (Y0 / 8 + bi) * 48 + (X0 / 8 + bj);
      cval[ci] = bv;
      cpos[ci] = bp;
    }
    return;
  }

  // ---- fp8 Gram-GEMM with relu-sum epilogue; swizzled LDS (R6) ----
  char* lA = smem2;
  char* lB = smem2 + 16384;
  float* r4 = (float*)(smem2 + 32768);

  int bx = blockIdx.x;
  int batch = bx / 136;
  int rem = bx % 136;
  int ti = 0, rowlen = 16;
  while (rem >= rowlen) { rem -= rowlen; rowlen--; ti++; }
  int tj = ti + rem;

  const unsigned char* Ab = descF8 + (size_t)batch * ND * DD;
  const float* inv = invn + batch * ND;
  int I0 = ti * 128, J0 = tj * 128;

  int tid = threadIdx.x;
  int wave = tid >> 6, lane = tid & 63;
  int rm = lane & 15, kq = lane >> 4;
  int wr = wave >> 1, wc = wave & 1;
  int lrow = lane >> 3;
  int lcolb = ((lane & 7) ^ lrow) << 4;   // swizzled source column (bytes)
  int cx = rm & 7;                        // read-side swizzle key

  f32x4 accf[4][4];
#pragma unroll
  for (int m = 0; m < 4; m++)
#pragma unroll
    for (int n = 0; n < 4; n++) accf[m][n] = (f32x4){0.f, 0.f, 0.f, 0.f};

  for (int k0 = 0; k0 < DD; k0 += 128) {
#pragma unroll
    for (int q = 0; q < 4; q++) {
      int chunk = wave * 4 + q;
      load_lds16(Ab + (size_t)(I0 + chunk * 8 + lrow) * DD + k0 + lcolb, lA + chunk * 1024);
      load_lds16(Ab + (size_t)(J0 + chunk * 8 + lrow) * DD + k0 + lcolb, lB + chunk * 1024);
    }
    __syncthreads();
#pragma unroll
    for (int kk = 0; kk < 128; kk += 32) {
      long af[4], bfr[4];
      int koff = kk + kq * 8;
      int pcol = ((((koff >> 4) ^ cx) << 4) | (koff & 8));
#pragma unroll
      for (int m = 0; m < 4; m++)
        af[m] = *reinterpret_cast<const long*>(lA + (wr * 64 + m * 16 + rm) * 128 + pcol);
#pragma unroll
      for (int n = 0; n < 4; n++)
        bfr[n] = *reinterpret_cast<const long*>(lB + (wc * 64 + n * 16 + rm) * 128 + pcol);
#pragma unroll
      for (int m = 0; m < 4; m++)
#pragma unroll
        for (int n = 0; n < 4; n++)
          accf[m][n] = __builtin_amdgcn_mfma_f32_16x16x32_fp8_fp8(af[m], bfr[n], accf[m][n], 0, 0, 0);
    }
    __syncthreads();
  }

  float wgt = (ti == tj) ? 1.f : 2.f;
  float invC[4];
#pragma unroll
  for (int n = 0; n < 4; n++) invC[n] = inv[J0 + wc * 64 + n * 16 + rm];
  float psum = 0.f;
#pragma unroll
  for (int m = 0; m < 4; m++) {
#pragma unroll
    for (int r = 0; r < 4; r++) {
      float invR = inv[I0 + wr * 64 + m * 16 + kq * 4 + r];
#pragma unroll
      for (int n = 0; n < 4; n++) psum += fmaxf(accf[m][n][r] * invR * invC[n], 0.f);
    }
  }
  psum *= wgt;
  for (int off = 32; off; off >>= 1) psum += __shfl_down(psum, off, 64);
  if (lane == 0) r4[wave] = psum;
  __syncthreads();
  if (tid == 0) pgemm[bx] = r4[0] + r4[1] + r4[2] + r4[3];
}

// ---------------------------------------------------------------------------
// STAGE 3: per-batch top-200 radix-select -> sum sd at corners -> pcorn[b].
// ---------------------------------------------------------------------------
__global__ __launch_bounds__(256) void topk_kernel(const float* __restrict__ cval,
                                                   const unsigned* __restrict__ cpos,
                                                   const float* __restrict__ sd,
                                                   float* __restrict__ pcorn) {
  __shared__ int hist[256];
  __shared__ int pick[2];
  __shared__ unsigned eqpos[256];
  __shared__ int eqcnt;
  __shared__ float rf[4];
  __shared__ int ri[4];

  int b = blockIdx.x;
  int t = threadIdx.x;
  int lane = t & 63;

  unsigned bits[9], pos[9];
#pragma unroll
  for (int q = 0; q < 9; q++) {
    int i = t + q * 256;
    unsigned vb = 0, p = 0;
    if (i < 2304) {
      float v = cval[b * 2304 + i];
      if (v > 0.f) { vb = __float_as_uint(v); p = cpos[b * 2304 + i]; }
    }
    bits[q] = vb; pos[q] = p;
  }

  int P = 0;
#pragma unroll
  for (int q = 0; q < 9; q++) P += (bits[q] != 0u);
  for (int off = 32; off; off >>= 1) P += __shfl_down(P, off, 64);
  if (lane == 0) ri[t >> 6] = P;
  __syncthreads();
  int Ptot = ri[0] + ri[1] + ri[2] + ri[3];
  if (Ptot == 0) { if (t == 0) pcorn[b] = 0.f; return; }
  int K = Ptot < 200 ? Ptot : 200;

  unsigned prefix = 0;
  int krem = K;
  for (int shift = 24; shift >= 0; shift -= 8) {
    hist[t] = 0;
    __syncthreads();
#pragma unroll
    for (int q = 0; q < 9; q++) {
      if (bits[q] != 0u &&
          (shift == 24 || (bits[q] >> (shift + 8)) == (prefix >> (shift + 8))))
        atomicAdd(&hist[(bits[q] >> shift) & 0xFF], 1);
    }
    __syncthreads();
    if (t < 64) {
      int h0 = hist[4 * t], h1 = hist[4 * t + 1], h2 = hist[4 * t + 2], h3 = hist[4 * t + 3];
      int tot = h0 + h1 + h2 + h3;
      int acc = tot;
      for (int d = 1; d < 64; d <<= 1) {
        int o = __shfl_down(acc, d, 64);
        if (t + d < 64) acc += o;
      }
      int excl = acc - tot;
      int G3 = excl, G2 = excl + h3, G1 = excl + h3 + h2, G0 = excl + h3 + h2 + h1;
      if (G0 < krem && G0 + h0 >= krem) { pick[0] = 4 * t;     pick[1] = G0; }
      if (G1 < krem && G1 + h1 >= krem) { pick[0] = 4 * t + 1; pick[1] = G1; }
      if (G2 < krem && G2 + h2 >= krem) { pick[0] = 4 * t + 2; pick[1] = G2; }
      if (G3 < krem && G3 + h3 >= krem) { pick[0] = 4 * t + 3; pick[1] = G3; }
    }
    __syncthreads();
    prefix |= ((unsigned)pick[0]) << shift;
    krem -= pick[1];
    __syncthreads();
  }

  if (t == 0) eqcnt = 0;
  __syncthreads();
  float s = 0.f;
#pragma unroll
  for (int q = 0; q < 9; q++) {
    if (bits[q] > prefix) s += sd[(size_t)b * HWSZ + pos[q]];
    else if (bits[q] != 0u && bits[q] == prefix) {
      int idx = atomicAdd(&eqcnt, 1);
      if (idx < 256) eqpos[idx] = pos[q];
    }
  }
  __syncthreads();
  int m = eqcnt;
  if (m <= krem) {
    if (t < m) s += sd[(size_t)b * HWSZ + eqpos[t]];
  } else {
    int mm = m < 256 ? m : 256;
    if (t < mm) {
      unsigned p = eqpos[t];
      int rank = 0;
      for (int u = 0; u < mm; u++) rank += (eqpos[u] < p);
      if (rank < krem) s += sd[(size_t)b * HWSZ + p];
    }
  }
  for (int off = 32; off; off >>= 1) s += __shfl_down(s, off, 64);
  if (lane == 0) rf[t >> 6] = s;
  __syncthreads();
  if (t == 0) pcorn[b] = rf[0] + rf[1] + rf[2] + rf[3];
}

// ---------------------------------------------------------------------------
// STAGE 4: final reduction over all partial arrays -> out[0].
// ---------------------------------------------------------------------------
__global__ __launch_bounds__(256) void finalize_kernel(const float* __restrict__ psoft,
                                                       const float* __restrict__ pcorn,
                                                       const float* __restrict__ pgemm,
                                                       float* __restrict__ out) {
  __shared__ float r4[4];
  float bce = 0.f;
  for (int i = threadIdx.x; i < 576; i += 256) bce += psoft[i];
  if (threadIdx.x < 16) bce -= pcorn[threadIdx.x];
  float g = 0.f;
  for (int i = threadIdx.x; i < 2176; i += 256) g += pgemm[i];
  float t = bce * (1.f / 2359296.f) + g * (1.f / 67108864.f);
  for (int off = 32; off; off >>= 1) t += __shfl_down(t, off, 64);
  if ((threadIdx.x & 63) == 0) r4[threadIdx.x >> 6] = t;
  __syncthreads();
  if (threadIdx.x == 0) out[0] = r4[0] + r4[1] + r4[2] + r4[3];
}

extern "C" void kernel_launch(void* const* d_in, const int* in_sizes, int n_in,
                              void* d_out, int out_size, void* d_ws, size_t ws_size,
                              hipStream_t stream) {
  (void)in_sizes; (void)n_in; (void)out_size; (void)ws_size;
  const float* desc = (const float*)d_in[0];
  const float* sd = (const float*)d_in[2];
  const float* imgs = (const float*)d_in[3];
  float* out = (float*)d_out;

  char* w = (char*)d_ws;
  float* resp = (float*)(w + OFF_RESP);
  float* cval = (float*)(w + OFF_CVAL);
  unsigned* cpos = (unsigned*)(w + OFF_CPOS);
  unsigned char* descF8 = (unsigned char*)(w + OFF_DESCB);
  float* invn = (float*)(w + OFF_INV);
  float* psoft = (float*)(w + OFF_PSOFT);
  float* pgemm = (float*)(w + OFF_PGEMM);
  float* pcorn = (float*)(w + OFF_PCORN);

  stage1_kernel<<<11072, 256, 0, stream>>>(imgs, resp, desc, descF8, invn,
                                           (const float4*)sd, psoft);
  stage2_kernel<<<2752, 256, 35456, stream>>>(descF8, invn, pgemm, resp, cval, cpos);
  topk_kernel<<<16, 256, 0, stream>>>(cval, cpos, sd, pcorn);
  finalize_kernel<<<1, 256, 0, stream>>>(psoft, pcorn, pgemm, out);
}

// Round 11
// 160.328 us; speedup vs baseline: 1.0867x; 1.0867x over previous
//
#include <hip/hip_runtime.h>

#define H 384
#define W 384
#define HWSZ (H * W)
#define NB 16
#define ND 2048
#define DD 256

// workspace byte offsets (all 256-aligned)
#define OFF_RESP  256
#define OFF_CVAL  9437440
#define OFF_CPOS  9584896
#define OFF_DESCB 9732352     // fp8 descriptors: 16*2048*256 = 8.4 MB
#define OFF_INV   26509568
#define OFF_PSOFT 26640640    // 576 floats
#define OFF_PGEMM 26643200    // 2176 floats
#define OFF_PCORN 26652160    // 16 floats

__device__ __forceinline__ int clampi(int v) { return v < 0 ? 0 : (v > 383 ? 383 : v); }
__device__ __forceinline__ int refl(int v) { return v < 0 ? -v : (v >= 384 ? 766 - v : v); }

// fp32 -> OCP e4m3fn with RNE. Layout: [s:1][eeee:4][mmm:3] -> s<<7 | e<<3 | m.
__device__ __forceinline__ unsigned f2e4m3(float x) {
  float a = fabsf(x);
  unsigned s = (__float_as_uint(x) >> 31) << 7;
  if (a >= 448.f) return s | 0x7E;
  if (a < 0.015625f) {
    int m = (int)rintf(a * 512.f);
    return s | (unsigned)m;
  }
  unsigned u = __float_as_uint(a);
  u += 0x7FFFF + ((u >> 20) & 1);
  unsigned e = (u >> 23) - 120;
  unsigned m = (u >> 20) & 7;
  return s | (e << 3) | m;
}

typedef float f32x4 __attribute__((ext_vector_type(4)));

__device__ __forceinline__ void load_lds16(const void* g, void* l) {
  __builtin_amdgcn_global_load_lds((const __attribute__((address_space(1))) void*)g,
                                   (__attribute__((address_space(3))) void*)l, 16, 0, 0);
}

// ---------------------------------------------------------------------------
// STAGE 1: resp (blocks 0..2303) || prep_desc (blocks 2304..10495).
// R7's verified scalar stencils (R8/R10 vectorization attempts both
// regressed: b128~12cyc vs b32~5.8cyc + layout conflicts ate the win).
// Only change vs R7: LDS shrunk 39.9 -> 32.4 KB by (a) t stride 33 -> 32
// (its access patterns are column-parallel c=tid%32 -> banks=c, 2-way=free)
// and (b) overlaying t onto gl (lifetimes barrier-separated).
// 32768 B/block x 5 = 160 KB -> 5 blocks/CU (was 4): +25% resident waves.
// ---------------------------------------------------------------------------
__global__ __launch_bounds__(256) void stage1_kernel(const float* __restrict__ imgs,
                                                     float* __restrict__ resp,
                                                     const float* __restrict__ desc,
                                                     unsigned char* __restrict__ descF8,
                                                     float* __restrict__ invn) {
  __shared__ float pbuf[4448];   // p0/p1/p2: 3 x [38][39]
  __shared__ float ubuf[3648];   // union: gl[40][41] (phases 0-1) / t0..t2 [38][32] (2-3)
  float* p0 = pbuf;
  float* p1 = pbuf + 1482;
  float* p2 = pbuf + 2964;
  float* glf = ubuf;             // stride 41
  float* t0 = ubuf;              // stride 32
  float* t1 = ubuf + 1216;
  float* t2 = ubuf + 2432;

  if (blockIdx.x >= 2304) {
    // ---- prep_desc: fp32 -> fp8 e4m3 + per-row inverse norm ----
    int wave = threadIdx.x >> 6, lane = threadIdx.x & 63;
    int row = (blockIdx.x - 2304) * 4 + wave;
    const float4* src = (const float4*)(desc + (size_t)row * DD);
    float4 v = src[lane];
    unsigned pk = f2e4m3(v.x) | (f2e4m3(v.y) << 8) | (f2e4m3(v.z) << 16) | (f2e4m3(v.w) << 24);
    ((unsigned*)(descF8 + (size_t)row * DD))[lane] = pk;
    float ss = v.x * v.x + v.y * v.y + v.z * v.z + v.w * v.w;
    for (int off = 32; off; off >>= 1) ss += __shfl_down(ss, off, 64);
    if (lane == 0) invn[row] = 1.f / fmaxf(sqrtf(ss), 1e-4f);
    return;
  }

  // ---- resp: gray -> sobel(edge) -> products -> 7x7 gauss(reflect) -> GFTT ----
  const float GW[7] = {0.0044330482f, 0.0540055826f, 0.2420362294f, 0.3990502160f,
                       0.2420362294f, 0.0540055826f, 0.0044330482f};
  int bid = blockIdx.x;
  int b = bid / 144;
  int t = bid % 144;
  int Y0 = (t / 12) * 32, X0 = (t % 12) * 32;
  const float* ib = imgs + (size_t)b * 3 * HWSZ;

  for (int i = threadIdx.x; i < 1600; i += 256) {
    int r = i / 40, c = i % 40;
    int gy = clampi(Y0 - 4 + r), gx = clampi(X0 - 4 + c);
    const float* p = ib + gy * W + gx;
    glf[r * 41 + c] = 0.299f * p[0] + 0.587f * p[HWSZ] + 0.114f * p[2 * HWSZ];
  }
  __syncthreads();

  bool interior = (X0 >= 32 && X0 <= 320 && Y0 >= 32 && Y0 <= 320);

  if (interior) {
    // Interior: refl/clamp are identity; py=Y0-3+r -> rows r..r+2, cols c..c+2.
    for (int i = threadIdx.x; i < 1444; i += 256) {
      int r = i / 38, c = i % 38;
      const float* g0 = glf + r * 41 + c;
      float a = g0[0],  bb = g0[1],  cc = g0[2];
      float d = g0[41],              e = g0[43];
      float f = g0[82], g = g0[83],  h = g0[84];
      float dx = 0.125f * ((cc - a) + 2.f * (e - d) + (h - f));
      float dy = 0.125f * ((f - a) + 2.f * (g - bb) + (h - cc));
      p0[r * 39 + c] = dx * dx;
      p1[r * 39 + c] = dy * dy;
      p2[r * 39 + c] = dx * dy;
    }
  } else {
    for (int i = threadIdx.x; i < 1444; i += 256) {
      int r = i / 38, c = i % 38;
      int py = refl(Y0 - 3 + r), px = refl(X0 - 3 + c);
      int ym = clampi(py - 1) - (Y0 - 4), y0 = py - (Y0 - 4), yp = clampi(py + 1) - (Y0 - 4);
      int xm = clampi(px - 1) - (X0 - 4), x0 = px - (X0 - 4), xp = clampi(px + 1) - (X0 - 4);
      float a = glf[ym * 41 + xm], bb = glf[ym * 41 + x0], cc = glf[ym * 41 + xp];
      float d = glf[y0 * 41 + xm], e = glf[y0 * 41 + xp];
      float f = glf[yp * 41 + xm], g = glf[yp * 41 + x0], h = glf[yp * 41 + xp];
      float dx = 0.125f * ((cc - a) + 2.f * (e - d) + (h - f));
      float dy = 0.125f * ((f - a) + 2.f * (g - bb) + (h - cc));
      p0[r * 39 + c] = dx * dx;
      p1[r * 39 + c] = dy * dy;
      p2[r * 39 + c] = dx * dy;
    }
  }
  __syncthreads();

  // horizontal gauss (gl dead; t overlays it — write after this barrier only)
  for (int i = threadIdx.x; i < 1216; i += 256) {
    int r = i / 32, c = i % 32;
    float s0 = 0.f, s1 = 0.f, s2 = 0.f;
#pragma unroll
    for (int j = 0; j < 7; j++) {
      s0 += GW[j] * p0[r * 39 + c + j];
      s1 += GW[j] * p1[r * 39 + c + j];
      s2 += GW[j] * p2[r * 39 + c + j];
    }
    t0[r * 32 + c] = s0; t1[r * 32 + c] = s1; t2[r * 32 + c] = s2;
  }
  __syncthreads();

  for (int i = threadIdx.x; i < 1024; i += 256) {
    int r = i / 32, c = i % 32;
    float s0 = 0.f, s1 = 0.f, s2 = 0.f;
#pragma unroll
    for (int j = 0; j < 7; j++) {
      s0 += GW[j] * t0[(r + j) * 32 + c];
      s1 += GW[j] * t1[(r + j) * 32 + c];
      s2 += GW[j] * t2[(r + j) * 32 + c];
    }
    float tr = s0 + s1;
    float det = s0 * s1 - s2 * s2;
    float disc = tr * tr - 4.f * det;
    float rv = 0.5f * (tr - sqrtf(fabsf(disc)));
    resp[(size_t)b * HWSZ + (Y0 + r) * W + (X0 + c)] = rv;
  }
}

// ---------------------------------------------------------------------------
// STAGE 2: nms (blocks 0..575) || softplus partials (blocks 576..1151).
// ---------------------------------------------------------------------------
__global__ __launch_bounds__(256) void stage2_kernel(const float* __restrict__ resp,
                                                     float* __restrict__ cval,
                                                     unsigned* __restrict__ cpos,
                                                     const float4* __restrict__ sd4,
                                                     float* __restrict__ psoft) {
  __shared__ float rl[68][69];
  __shared__ float nl[64][65];
  __shared__ float r4[4];

  if (blockIdx.x >= 576) {
    // ---- softplus partial sums ----
    int sb = blockIdx.x - 576;
    float s = 0.f;
    int base = sb * 256 + threadIdx.x;
#pragma unroll
    for (int it = 0; it < 4; it++) {
      float4 v = sd4[base + it * 147456];
      s += fmaxf(v.x, 0.f) + log1pf(expf(-fabsf(v.x))) +
           fmaxf(v.y, 0.f) + log1pf(expf(-fabsf(v.y))) +
           fmaxf(v.z, 0.f) + log1pf(expf(-fabsf(v.z))) +
           fmaxf(v.w, 0.f) + log1pf(expf(-fabsf(v.w)));
    }
    for (int off = 32; off; off >>= 1) s += __shfl_down(s, off, 64);
    if ((threadIdx.x & 63) == 0) r4[threadIdx.x >> 6] = s;
    __syncthreads();
    if (threadIdx.x == 0) psoft[sb] = r4[0] + r4[1] + r4[2] + r4[3];
    return;
  }

  // ---- 5x5 NMS (-inf border) + per-8x8-block max candidate ----
  int bid = blockIdx.x;
  int b = bid / 36;
  int t = bid % 36;
  int Y0 = (t / 6) * 64, X0 = (t % 6) * 64;
  const float* rb = resp + (size_t)b * HWSZ;

  for (int i = threadIdx.x; i < 68 * 68; i += 256) {
    int r = i / 68, c = i % 68;
    int gy = Y0 - 2 + r, gx = X0 - 2 + c;
    float v = -INFINITY;
    if (gy >= 0 && gy < H && gx >= 0 && gx < W) v = rb[gy * W + gx];
    rl[r][c] = v;
  }
  __syncthreads();

  for (int i = threadIdx.x; i < 4096; i += 256) {
    int r = i / 64, c = i % 64;
    float m = -INFINITY;
#pragma unroll
    for (int dr = 0; dr < 5; dr++)
#pragma unroll
      for (int dc = 0; dc < 5; dc++) m = fmaxf(m, rl[r + dr][c + dc]);
    float v = rl[r + 2][c + 2];
    nl[r][c] = (v == m) ? v : 0.f;
  }
  __syncthreads();

  if (threadIdx.x < 64) {
    int bi = threadIdx.x / 8, bj = threadIdx.x % 8;
    float bv = 0.f;
    unsigned bp = 0;
    for (int rr = 0; rr < 8; rr++)
      for (int cc = 0; cc < 8; cc++) {
        float v = nl[bi * 8 + rr][bj * 8 + cc];
        if (v > bv) { bv = v; bp = (unsigned)((Y0 + bi * 8 + rr) * W + (X0 + bj * 8 + cc)); }
      }
    int ci = b * 2304 + (Y0 / 8 + bi) * 48 + (X0 / 8 + bj);
    cval[ci] = bv;
    cpos[ci] = bp;
  }
}

// ---------------------------------------------------------------------------
// STAGE 3: topk radix-select (blocks 0..15, latency hides under gemm) ||
// fp8 Gram-GEMM relu-sum (blocks 16..2191), swizzled LDS (R6).
// ---------------------------------------------------------------------------
__global__ __launch_bounds__(256) void stage3_kernel(const float* __restrict__ cval,
                                                     const unsigned* __restrict__ cpos,
                                                     const float* __restrict__ sd,
                                                     float* __restrict__ pcorn,
                                                     const unsigned char* __restrict__ descF8,
                                                     const float* __restrict__ invn,
                                                     float* __restrict__ pgemm) {
  // gemm shared
  __shared__ char lA[128 * 128];
  __shared__ char lB[128 * 128];
  __shared__ float r4[4];
  // topk shared
  __shared__ int hist[256];
  __shared__ int pick[2];
  __shared__ unsigned eqpos[256];
  __shared__ int eqcnt;
  __shared__ int ri[4];

  if (blockIdx.x < 16) {
    int b = blockIdx.x;
    int t = threadIdx.x;
    int lane = t & 63;

    unsigned bits[9], pos[9];
#pragma unroll
    for (int q = 0; q < 9; q++) {
      int i = t + q * 256;
      unsigned vb = 0, p = 0;
      if (i < 2304) {
        float v = cval[b * 2304 + i];
        if (v > 0.f) { vb = __float_as_uint(v); p = cpos[b * 2304 + i]; }
      }
      bits[q] = vb; pos[q] = p;
    }

    int P = 0;
#pragma unroll
    for (int q = 0; q < 9; q++) P += (bits[q] != 0u);
    for (int off = 32; off; off >>= 1) P += __shfl_down(P, off, 64);
    if (lane == 0) ri[t >> 6] = P;
    __syncthreads();
    int Ptot = ri[0] + ri[1] + ri[2] + ri[3];
    if (Ptot == 0) { if (t == 0) pcorn[b] = 0.f; return; }
    int K = Ptot < 200 ? Ptot : 200;

    unsigned prefix = 0;
    int krem = K;
    for (int shift = 24; shift >= 0; shift -= 8) {
      hist[t] = 0;
      __syncthreads();
#pragma unroll
      for (int q = 0; q < 9; q++) {
        if (bits[q] != 0u &&
            (shift == 24 || (bits[q] >> (shift + 8)) == (prefix >> (shift + 8))))
          atomicAdd(&hist[(bits[q] >> shift) & 0xFF], 1);
      }
      __syncthreads();
      if (t < 64) {
        int h0 = hist[4 * t], h1 = hist[4 * t + 1], h2 = hist[4 * t + 2], h3 = hist[4 * t + 3];
        int tot = h0 + h1 + h2 + h3;
        int acc = tot;
        for (int d = 1; d < 64; d <<= 1) {
          int o = __shfl_down(acc, d, 64);
          if (t + d < 64) acc += o;
        }
        int excl = acc - tot;
        int G3 = excl, G2 = excl + h3, G1 = excl + h3 + h2, G0 = excl + h3 + h2 + h1;
        if (G0 < krem && G0 + h0 >= krem) { pick[0] = 4 * t;     pick[1] = G0; }
        if (G1 < krem && G1 + h1 >= krem) { pick[0] = 4 * t + 1; pick[1] = G1; }
        if (G2 < krem && G2 + h2 >= krem) { pick[0] = 4 * t + 2; pick[1] = G2; }
        if (G3 < krem && G3 + h3 >= krem) { pick[0] = 4 * t + 3; pick[1] = G3; }
      }
      __syncthreads();
      prefix |= ((unsigned)pick[0]) << shift;
      krem -= pick[1];
      __syncthreads();
    }

    if (t == 0) eqcnt = 0;
    __syncthreads();
    float s = 0.f;
#pragma unroll
    for (int q = 0; q < 9; q++) {
      if (bits[q] > prefix) s += sd[(size_t)b * HWSZ + pos[q]];
      else if (bits[q] != 0u && bits[q] == prefix) {
        int idx = atomicAdd(&eqcnt, 1);
        if (idx < 256) eqpos[idx] = pos[q];
      }
    }
    __syncthreads();
    int m = eqcnt;
    if (m <= krem) {
      if (t < m) s += sd[(size_t)b * HWSZ + eqpos[t]];
    } else {
      int mm = m < 256 ? m : 256;
      if (t < mm) {
        unsigned p = eqpos[t];
        int rank = 0;
        for (int u = 0; u < mm; u++) rank += (eqpos[u] < p);
        if (rank < krem) s += sd[(size_t)b * HWSZ + p];
      }
    }
    for (int off = 32; off; off >>= 1) s += __shfl_down(s, off, 64);
    if (lane == 0) r4[t >> 6] = s;
    __syncthreads();
    if (t == 0) pcorn[b] = r4[0] + r4[1] + r4[2] + r4[3];
    return;
  }

  // ---- fp8 Gram-GEMM with relu-sum epilogue; swizzled LDS ----
  int bx = blockIdx.x - 16;
  int batch = bx / 136;
  int rem = bx % 136;
  int ti = 0, rowlen = 16;
  while (rem >= rowlen) { rem -= rowlen; rowlen--; ti++; }
  int tj = ti + rem;

  const unsigned char* Ab = descF8 + (size_t)batch * ND * DD;
  const float* inv = invn + batch * ND;
  int I0 = ti * 128, J0 = tj * 128;

  int tid = threadIdx.x;
  int wave = tid >> 6, lane = tid & 63;
  int rm = lane & 15, kq = lane >> 4;
  int wr = wave >> 1, wc = wave & 1;
  int lrow = lane >> 3;
  int lcolb = ((lane & 7) ^ lrow) << 4;   // swizzled source column (bytes)
  int cx = rm & 7;                        // read-side swizzle key

  f32x4 accf[4][4];
#pragma unroll
  for (int m = 0; m < 4; m++)
#pragma unroll
    for (int n = 0; n < 4; n++) accf[m][n] = (f32x4){0.f, 0.f, 0.f, 0.f};

  for (int k0 = 0; k0 < DD; k0 += 128) {
#pragma unroll
    for (int q = 0; q < 4; q++) {
      int chunk = wave * 4 + q;
      load_lds16(Ab + (size_t)(I0 + chunk * 8 + lrow) * DD + k0 + lcolb, lA + chunk * 1024);
      load_lds16(Ab + (size_t)(J0 + chunk * 8 + lrow) * DD + k0 + lcolb, lB + chunk * 1024);
    }
    __syncthreads();
#pragma unroll
    for (int kk = 0; kk < 128; kk += 32) {
      long af[4], bfr[4];
      int koff = kk + kq * 8;
      int pcol = ((((koff >> 4) ^ cx) << 4) | (koff & 8));
#pragma unroll
      for (int m = 0; m < 4; m++)
        af[m] = *reinterpret_cast<const long*>(lA + (wr * 64 + m * 16 + rm) * 128 + pcol);
#pragma unroll
      for (int n = 0; n < 4; n++)
        bfr[n] = *reinterpret_cast<const long*>(lB + (wc * 64 + n * 16 + rm) * 128 + pcol);
#pragma unroll
      for (int m = 0; m < 4; m++)
#pragma unroll
        for (int n = 0; n < 4; n++)
          accf[m][n] = __builtin_amdgcn_mfma_f32_16x16x32_fp8_fp8(af[m], bfr[n], accf[m][n], 0, 0, 0);
    }
    __syncthreads();
  }

  float wgt = (ti == tj) ? 1.f : 2.f;
  float invC[4];
#pragma unroll
  for (int n = 0; n < 4; n++) invC[n] = inv[J0 + wc * 64 + n * 16 + rm];
  float psum = 0.f;
#pragma unroll
  for (int m = 0; m < 4; m++) {
#pragma unroll
    for (int r = 0; r < 4; r++) {
      float invR = inv[I0 + wr * 64 + m * 16 + kq * 4 + r];
#pragma unroll
      for (int n = 0; n < 4; n++) psum += fmaxf(accf[m][n][r] * invR * invC[n], 0.f);
    }
  }
  psum *= wgt;
  for (int off = 32; off; off >>= 1) psum += __shfl_down(psum, off, 64);
  if (lane == 0) r4[wave] = psum;
  __syncthreads();
  if (tid == 0) pgemm[bx] = r4[0] + r4[1] + r4[2] + r4[3];
}

// ---------------------------------------------------------------------------
// STAGE 4: final reduction over all partial arrays -> out[0].
// ---------------------------------------------------------------------------
__global__ __launch_bounds__(256) void finalize_kernel(const float* __restrict__ psoft,
                                                       const float* __restrict__ pcorn,
                                                       const float* __restrict__ pgemm,
                                                       float* __restrict__ out) {
  __shared__ float r4[4];
  float bce = 0.f;
  for (int i = threadIdx.x; i < 576; i += 256) bce += psoft[i];
  if (threadIdx.x < 16) bce -= pcorn[threadIdx.x];
  float g = 0.f;
  for (int i = threadIdx.x; i < 2176; i += 256) g += pgemm[i];
  float t = bce * (1.f / 2359296.f) + g * (1.f / 67108864.f);
  for (int off = 32; off; off >>= 1) t += __shfl_down(t, off, 64);
  if ((threadIdx.x & 63) == 0) r4[threadIdx.x >> 6] = t;
  __syncthreads();
  if (threadIdx.x == 0) out[0] = r4[0] + r4[1] + r4[2] + r4[3];
}

extern "C" void kernel_launch(void* const* d_in, const int* in_sizes, int n_in,
                              void* d_out, int out_size, void* d_ws, size_t ws_size,
                              hipStream_t stream) {
  (void)in_sizes; (void)n_in; (void)out_size; (void)ws_size;
  const float* desc = (const float*)d_in[0];
  const float* sd = (const float*)d_in[2];
  const float* imgs = (const float*)d_in[3];
  float* out = (float*)d_out;

  char* w = (char*)d_ws;
  float* resp = (float*)(w + OFF_RESP);
  float* cval = (float*)(w + OFF_CVAL);
  unsigned* cpos = (unsigned*)(w + OFF_CPOS);
  unsigned char* descF8 = (unsigned char*)(w + OFF_DESCB);
  float* invn = (float*)(w + OFF_INV);
  float* psoft = (float*)(w + OFF_PSOFT);
  float* pgemm = (float*)(w + OFF_PGEMM);
  float* pcorn = (float*)(w + OFF_PCORN);

  stage1_kernel<<<10496, 256, 0, stream>>>(imgs, resp, desc, descF8, invn);
  stage2_kernel<<<1152, 256, 0, stream>>>(resp, cval, cpos, (const float4*)sd, psoft);
  stage3_kernel<<<2192, 256, 0, stream>>>(cval, cpos, sd, pcorn, descF8, invn, pgemm);
  finalize_kernel<<<1, 256, 0, stream>>>(psoft, pcorn, pgemm, out);
}

// Round 12
// 159.984 us; speedup vs baseline: 1.0890x; 1.0022x over previous
//
#include <hip/hip_runtime.h>

#define H 384
#define W 384
#define HWSZ (H * W)
#define NB 16
#define ND 2048
#define DD 256

// workspace byte offsets (all 256-aligned)
#define OFF_RESP  256
#define OFF_CVAL  9437440
#define OFF_CPOS  9584896
#define OFF_DESCB 9732352     // fp8 descriptors: 16*2048*256 = 8.4 MB
#define OFF_INV   26509568
#define OFF_PSOFT 26640640    // 576 floats
#define OFF_PGEMM 26643200    // 2176 floats
#define OFF_PCORN 26652160    // 16 floats

__device__ __forceinline__ int clampi(int v) { return v < 0 ? 0 : (v > 383 ? 383 : v); }
__device__ __forceinline__ int refl(int v) { return v < 0 ? -v : (v >= 384 ? 766 - v : v); }

// fp32 -> OCP e4m3fn with RNE. Layout: [s:1][eeee:4][mmm:3] -> s<<7 | e<<3 | m.
__device__ __forceinline__ unsigned f2e4m3(float x) {
  float a = fabsf(x);
  unsigned s = (__float_as_uint(x) >> 31) << 7;
  if (a >= 448.f) return s | 0x7E;
  if (a < 0.015625f) {
    int m = (int)rintf(a * 512.f);
    return s | (unsigned)m;
  }
  unsigned u = __float_as_uint(a);
  u += 0x7FFFF + ((u >> 20) & 1);
  unsigned e = (u >> 23) - 120;
  unsigned m = (u >> 20) & 7;
  return s | (e << 3) | m;
}

typedef float f32x4 __attribute__((ext_vector_type(4)));

__device__ __forceinline__ void load_lds16(const void* g, void* l) {
  __builtin_amdgcn_global_load_lds((const __attribute__((address_space(1))) void*)g,
                                   (__attribute__((address_space(3))) void*)l, 16, 0, 0);
}

// ---------------------------------------------------------------------------
// STAGE 1: resp (blocks 0..2303) || prep_desc (blocks 2304..10495).
// vs R11 (equal-best 160.3): gauss passes now use scalar b32 sliding windows
// — 4 consecutive outputs per thread, 10 reads/array instead of 28 (the safe
// form of R8/R10's idea: no b128 (12cyc vs 5.8), no spill (~22 live regs),
// audited conflict-free: horiz banks (7r+4k+dc) give rows r,r+4 sharing ->
// 2-way = free; vert banks = c -> 2-way = free). Accumulation order per
// output unchanged -> bitwise identical. LDS 32 KB -> 5 blocks/CU.
// ---------------------------------------------------------------------------
__global__ __launch_bounds__(256) void stage1_kernel(const float* __restrict__ imgs,
                                                     float* __restrict__ resp,
                                                     const float* __restrict__ desc,
                                                     unsigned char* __restrict__ descF8,
                                                     float* __restrict__ invn) {
  __shared__ float pbuf[4448];   // p0/p1/p2: 3 x [38][39]
  __shared__ float ubuf[3648];   // union: gl[40][41] (phases 0-1) / t0..t2 [38][32] (2-3)
  float* p0 = pbuf;
  float* p1 = pbuf + 1482;
  float* p2 = pbuf + 2964;
  float* glf = ubuf;             // stride 41
  float* t0 = ubuf;              // stride 32
  float* t1 = ubuf + 1216;
  float* t2 = ubuf + 2432;

  if (blockIdx.x >= 2304) {
    // ---- prep_desc: fp32 -> fp8 e4m3 + per-row inverse norm ----
    int wave = threadIdx.x >> 6, lane = threadIdx.x & 63;
    int row = (blockIdx.x - 2304) * 4 + wave;
    const float4* src = (const float4*)(desc + (size_t)row * DD);
    float4 v = src[lane];
    unsigned pk = f2e4m3(v.x) | (f2e4m3(v.y) << 8) | (f2e4m3(v.z) << 16) | (f2e4m3(v.w) << 24);
    ((unsigned*)(descF8 + (size_t)row * DD))[lane] = pk;
    float ss = v.x * v.x + v.y * v.y + v.z * v.z + v.w * v.w;
    for (int off = 32; off; off >>= 1) ss += __shfl_down(ss, off, 64);
    if (lane == 0) invn[row] = 1.f / fmaxf(sqrtf(ss), 1e-4f);
    return;
  }

  // ---- resp: gray -> sobel(edge) -> products -> 7x7 gauss(reflect) -> GFTT ----
  const float GW[7] = {0.0044330482f, 0.0540055826f, 0.2420362294f, 0.3990502160f,
                       0.2420362294f, 0.0540055826f, 0.0044330482f};
  int bid = blockIdx.x;
  int b = bid / 144;
  int t = bid % 144;
  int Y0 = (t / 12) * 32, X0 = (t % 12) * 32;
  const float* ib = imgs + (size_t)b * 3 * HWSZ;

  for (int i = threadIdx.x; i < 1600; i += 256) {
    int r = i / 40, c = i % 40;
    int gy = clampi(Y0 - 4 + r), gx = clampi(X0 - 4 + c);
    const float* p = ib + gy * W + gx;
    glf[r * 41 + c] = 0.299f * p[0] + 0.587f * p[HWSZ] + 0.114f * p[2 * HWSZ];
  }
  __syncthreads();

  bool interior = (X0 >= 32 && X0 <= 320 && Y0 >= 32 && Y0 <= 320);

  if (interior) {
    // Interior: refl/clamp are identity; py=Y0-3+r -> rows r..r+2, cols c..c+2.
    for (int i = threadIdx.x; i < 1444; i += 256) {
      int r = i / 38, c = i % 38;
      const float* g0 = glf + r * 41 + c;
      float a = g0[0],  bb = g0[1],  cc = g0[2];
      float d = g0[41],              e = g0[43];
      float f = g0[82], g = g0[83],  h = g0[84];
      float dx = 0.125f * ((cc - a) + 2.f * (e - d) + (h - f));
      float dy = 0.125f * ((f - a) + 2.f * (g - bb) + (h - cc));
      p0[r * 39 + c] = dx * dx;
      p1[r * 39 + c] = dy * dy;
      p2[r * 39 + c] = dx * dy;
    }
  } else {
    for (int i = threadIdx.x; i < 1444; i += 256) {
      int r = i / 38, c = i % 38;
      int py = refl(Y0 - 3 + r), px = refl(X0 - 3 + c);
      int ym = clampi(py - 1) - (Y0 - 4), y0 = py - (Y0 - 4), yp = clampi(py + 1) - (Y0 - 4);
      int xm = clampi(px - 1) - (X0 - 4), x0 = px - (X0 - 4), xp = clampi(px + 1) - (X0 - 4);
      float a = glf[ym * 41 + xm], bb = glf[ym * 41 + x0], cc = glf[ym * 41 + xp];
      float d = glf[y0 * 41 + xm], e = glf[y0 * 41 + xp];
      float f = glf[yp * 41 + xm], g = glf[yp * 41 + x0], h = glf[yp * 41 + xp];
      float dx = 0.125f * ((cc - a) + 2.f * (e - d) + (h - f));
      float dy = 0.125f * ((f - a) + 2.f * (g - bb) + (h - cc));
      p0[r * 39 + c] = dx * dx;
      p1[r * 39 + c] = dy * dy;
      p2[r * 39 + c] = dx * dy;
    }
  }
  __syncthreads();

  // horizontal gauss: 4 outputs/thread via 10-wide scalar sliding window.
  // 304 groups: r = g>>3 (0..37), c0 = (g&7)*4 (0..28). Arrays sequential
  // to bound live registers. (gl dead; t overlays it.)
  for (int g = threadIdx.x; g < 304; g += 256) {
    int r = g >> 3, c0 = (g & 7) * 4;
    {
      float a[10];
#pragma unroll
      for (int dc = 0; dc < 10; dc++) a[dc] = p0[r * 39 + c0 + dc];
#pragma unroll
      for (int k = 0; k < 4; k++) {
        float sv = 0.f;
#pragma unroll
        for (int j = 0; j < 7; j++) sv += GW[j] * a[k + j];
        t0[r * 32 + c0 + k] = sv;
      }
    }
    {
      float a[10];
#pragma unroll
      for (int dc = 0; dc < 10; dc++) a[dc] = p1[r * 39 + c0 + dc];
#pragma unroll
      for (int k = 0; k < 4; k++) {
        float sv = 0.f;
#pragma unroll
        for (int j = 0; j < 7; j++) sv += GW[j] * a[k + j];
        t1[r * 32 + c0 + k] = sv;
      }
    }
    {
      float a[10];
#pragma unroll
      for (int dc = 0; dc < 10; dc++) a[dc] = p2[r * 39 + c0 + dc];
#pragma unroll
      for (int k = 0; k < 4; k++) {
        float sv = 0.f;
#pragma unroll
        for (int j = 0; j < 7; j++) sv += GW[j] * a[k + j];
        t2[r * 32 + c0 + k] = sv;
      }
    }
  }
  __syncthreads();

  // vertical gauss + GFTT: 4 rows/thread via 10-deep sliding window
  // (exactly 256 groups: r0 = (tid>>5)*4, c = tid&31; banks = c -> free).
  {
    int r0 = (threadIdx.x >> 5) * 4, c = threadIdx.x & 31;
    float s0[4], s1[4], s2[4];
    {
      float a[10];
#pragma unroll
      for (int dr = 0; dr < 10; dr++) a[dr] = t0[(r0 + dr) * 32 + c];
#pragma unroll
      for (int k = 0; k < 4; k++) {
        float sv = 0.f;
#pragma unroll
        for (int j = 0; j < 7; j++) sv += GW[j] * a[k + j];
        s0[k] = sv;
      }
    }
    {
      float a[10];
#pragma unroll
      for (int dr = 0; dr < 10; dr++) a[dr] = t1[(r0 + dr) * 32 + c];
#pragma unroll
      for (int k = 0; k < 4; k++) {
        float sv = 0.f;
#pragma unroll
        for (int j = 0; j < 7; j++) sv += GW[j] * a[k + j];
        s1[k] = sv;
      }
    }
    {
      float a[10];
#pragma unroll
      for (int dr = 0; dr < 10; dr++) a[dr] = t2[(r0 + dr) * 32 + c];
#pragma unroll
      for (int k = 0; k < 4; k++) {
        float sv = 0.f;
#pragma unroll
        for (int j = 0; j < 7; j++) sv += GW[j] * a[k + j];
        s2[k] = sv;
      }
    }
#pragma unroll
    for (int k = 0; k < 4; k++) {
      float tr = s0[k] + s1[k];
      float det = s0[k] * s1[k] - s2[k] * s2[k];
      float disc = tr * tr - 4.f * det;
      float rv = 0.5f * (tr - sqrtf(fabsf(disc)));
      resp[(size_t)b * HWSZ + (Y0 + r0 + k) * W + (X0 + c)] = rv;
    }
  }
}

// ---------------------------------------------------------------------------
// STAGE 2: nms (blocks 0..575) || softplus partials (blocks 576..1151).
// ---------------------------------------------------------------------------
__global__ __launch_bounds__(256) void stage2_kernel(const float* __restrict__ resp,
                                                     float* __restrict__ cval,
                                                     unsigned* __restrict__ cpos,
                                                     const float4* __restrict__ sd4,
                                                     float* __restrict__ psoft) {
  __shared__ float rl[68][69];
  __shared__ float nl[64][65];
  __shared__ float r4[4];

  if (blockIdx.x >= 576) {
    // ---- softplus partial sums ----
    int sb = blockIdx.x - 576;
    float s = 0.f;
    int base = sb * 256 + threadIdx.x;
#pragma unroll
    for (int it = 0; it < 4; it++) {
      float4 v = sd4[base + it * 147456];
      s += fmaxf(v.x, 0.f) + log1pf(expf(-fabsf(v.x))) +
           fmaxf(v.y, 0.f) + log1pf(expf(-fabsf(v.y))) +
           fmaxf(v.z, 0.f) + log1pf(expf(-fabsf(v.z))) +
           fmaxf(v.w, 0.f) + log1pf(expf(-fabsf(v.w)));
    }
    for (int off = 32; off; off >>= 1) s += __shfl_down(s, off, 64);
    if ((threadIdx.x & 63) == 0) r4[threadIdx.x >> 6] = s;
    __syncthreads();
    if (threadIdx.x == 0) psoft[sb] = r4[0] + r4[1] + r4[2] + r4[3];
    return;
  }

  // ---- 5x5 NMS (-inf border) + per-8x8-block max candidate ----
  int bid = blockIdx.x;
  int b = bid / 36;
  int t = bid % 36;
  int Y0 = (t / 6) * 64, X0 = (t % 6) * 64;
  const float* rb = resp + (size_t)b * HWSZ;

  for (int i = threadIdx.x; i < 68 * 68; i += 256) {
    int r = i / 68, c = i % 68;
    int gy = Y0 - 2 + r, gx = X0 - 2 + c;
    float v = -INFINITY;
    if (gy >= 0 && gy < H && gx >= 0 && gx < W) v = rb[gy * W + gx];
    rl[r][c] = v;
  }
  __syncthreads();

  for (int i = threadIdx.x; i < 4096; i += 256) {
    int r = i / 64, c = i % 64;
    float m = -INFINITY;
#pragma unroll
    for (int dr = 0; dr < 5; dr++)
#pragma unroll
      for (int dc = 0; dc < 5; dc++) m = fmaxf(m, rl[r + dr][c + dc]);
    float v = rl[r + 2][c + 2];
    nl[r][c] = (v == m) ? v : 0.f;
  }
  __syncthreads();

  if (threadIdx.x < 64) {
    int bi = threadIdx.x / 8, bj = threadIdx.x % 8;
    float bv = 0.f;
    unsigned bp = 0;
    for (int rr = 0; rr < 8; rr++)
      for (int cc = 0; cc < 8; cc++) {
        float v = nl[bi * 8 + rr][bj * 8 + cc];
        if (v > bv) { bv = v; bp = (unsigned)((Y0 + bi * 8 + rr) * W + (X0 + bj * 8 + cc)); }
      }
    int ci = b * 2304 + (Y0 / 8 + bi) * 48 + (X0 / 8 + bj);
    cval[ci] = bv;
    cpos[ci] = bp;
  }
}

// ---------------------------------------------------------------------------
// STAGE 3: topk radix-select (blocks 0..15, latency hides under gemm) ||
// fp8 Gram-GEMM relu-sum (blocks 16..2191), swizzled LDS (R6).
// ---------------------------------------------------------------------------
__global__ __launch_bounds__(256) void stage3_kernel(const float* __restrict__ cval,
                                                     const unsigned* __restrict__ cpos,
                                                     const float* __restrict__ sd,
                                                     float* __restrict__ pcorn,
                                                     const unsigned char* __restrict__ descF8,
                                                     const float* __restrict__ invn,
                                                     float* __restrict__ pgemm) {
  // gemm shared
  __shared__ char lA[128 * 128];
  __shared__ char lB[128 * 128];
  __shared__ float r4[4];
  // topk shared
  __shared__ int hist[256];
  __shared__ int pick[2];
  __shared__ unsigned eqpos[256];
  __shared__ int eqcnt;
  __shared__ int ri[4];

  if (blockIdx.x < 16) {
    int b = blockIdx.x;
    int t = threadIdx.x;
    int lane = t & 63;

    unsigned bits[9], pos[9];
#pragma unroll
    for (int q = 0; q < 9; q++) {
      int i = t + q * 256;
      unsigned vb = 0, p = 0;
      if (i < 2304) {
        float v = cval[b * 2304 + i];
        if (v > 0.f) { vb = __float_as_uint(v); p = cpos[b * 2304 + i]; }
      }
      bits[q] = vb; pos[q] = p;
    }

    int P = 0;
#pragma unroll
    for (int q = 0; q < 9; q++) P += (bits[q] != 0u);
    for (int off = 32; off; off >>= 1) P += __shfl_down(P, off, 64);
    if (lane == 0) ri[t >> 6] = P;
    __syncthreads();
    int Ptot = ri[0] + ri[1] + ri[2] + ri[3];
    if (Ptot == 0) { if (t == 0) pcorn[b] = 0.f; return; }
    int K = Ptot < 200 ? Ptot : 200;

    unsigned prefix = 0;
    int krem = K;
    for (int shift = 24; shift >= 0; shift -= 8) {
      hist[t] = 0;
      __syncthreads();
#pragma unroll
      for (int q = 0; q < 9; q++) {
        if (bits[q] != 0u &&
            (shift == 24 || (bits[q] >> (shift + 8)) == (prefix >> (shift + 8))))
          atomicAdd(&hist[(bits[q] >> shift) & 0xFF], 1);
      }
      __syncthreads();
      if (t < 64) {
        int h0 = hist[4 * t], h1 = hist[4 * t + 1], h2 = hist[4 * t + 2], h3 = hist[4 * t + 3];
        int tot = h0 + h1 + h2 + h3;
        int acc = tot;
        for (int d = 1; d < 64; d <<= 1) {
          int o = __shfl_down(acc, d, 64);
          if (t + d < 64) acc += o;
        }
        int excl = acc - tot;
        int G3 = excl, G2 = excl + h3, G1 = excl + h3 + h2, G0 = excl + h3 + h2 + h1;
        if (G0 < krem && G0 + h0 >= krem) { pick[0] = 4 * t;     pick[1] = G0; }
        if (G1 < krem && G1 + h1 >= krem) { pick[0] = 4 * t + 1; pick[1] = G1; }
        if (G2 < krem && G2 + h2 >= krem) { pick[0] = 4 * t + 2; pick[1] = G2; }
        if (G3 < krem && G3 + h3 >= krem) { pick[0] = 4 * t + 3; pick[1] = G3; }
      }
      __syncthreads();
      prefix |= ((unsigned)pick[0]) << shift;
      krem -= pick[1];
      __syncthreads();
    }

    if (t == 0) eqcnt = 0;
    __syncthreads();
    float s = 0.f;
#pragma unroll
    for (int q = 0; q < 9; q++) {
      if (bits[q] > prefix) s += sd[(size_t)b * HWSZ + pos[q]];
      else if (bits[q] != 0u && bits[q] == prefix) {
        int idx = atomicAdd(&eqcnt, 1);
        if (idx < 256) eqpos[idx] = pos[q];
      }
    }
    __syncthreads();
    int m = eqcnt;
    if (m <= krem) {
      if (t < m) s += sd[(size_t)b * HWSZ + eqpos[t]];
    } else {
      int mm = m < 256 ? m : 256;
      if (t < mm) {
        unsigned p = eqpos[t];
        int rank = 0;
        for (int u = 0; u < mm; u++) rank += (eqpos[u] < p);
        if (rank < krem) s += sd[(size_t)b * HWSZ + p];
      }
    }
    for (int off = 32; off; off >>= 1) s += __shfl_down(s, off, 64);
    if (lane == 0) r4[t >> 6] = s;
    __syncthreads();
    if (t == 0) pcorn[b] = r4[0] + r4[1] + r4[2] + r4[3];
    return;
  }

  // ---- fp8 Gram-GEMM with relu-sum epilogue; swizzled LDS ----
  int bx = blockIdx.x - 16;
  int batch = bx / 136;
  int rem = bx % 136;
  int ti = 0, rowlen = 16;
  while (rem >= rowlen) { rem -= rowlen; rowlen--; ti++; }
  int tj = ti + rem;

  const unsigned char* Ab = descF8 + (size_t)batch * ND * DD;
  const float* inv = invn + batch * ND;
  int I0 = ti * 128, J0 = tj * 128;

  int tid = threadIdx.x;
  int wave = tid >> 6, lane = tid & 63;
  int rm = lane & 15, kq = lane >> 4;
  int wr = wave >> 1, wc = wave & 1;
  int lrow = lane >> 3;
  int lcolb = ((lane & 7) ^ lrow) << 4;   // swizzled source column (bytes)
  int cx = rm & 7;                        // read-side swizzle key

  f32x4 accf[4][4];
#pragma unroll
  for (int m = 0; m < 4; m++)
#pragma unroll
    for (int n = 0; n < 4; n++) accf[m][n] = (f32x4){0.f, 0.f, 0.f, 0.f};

  for (int k0 = 0; k0 < DD; k0 += 128) {
#pragma unroll
    for (int q = 0; q < 4; q++) {
      int chunk = wave * 4 + q;
      load_lds16(Ab + (size_t)(I0 + chunk * 8 + lrow) * DD + k0 + lcolb, lA + chunk * 1024);
      load_lds16(Ab + (size_t)(J0 + chunk * 8 + lrow) * DD + k0 + lcolb, lB + chunk * 1024);
    }
    __syncthreads();
#pragma unroll
    for (int kk = 0; kk < 128; kk += 32) {
      long af[4], bfr[4];
      int koff = kk + kq * 8;
      int pcol = ((((koff >> 4) ^ cx) << 4) | (koff & 8));
#pragma unroll
      for (int m = 0; m < 4; m++)
        af[m] = *reinterpret_cast<const long*>(lA + (wr * 64 + m * 16 + rm) * 128 + pcol);
#pragma unroll
      for (int n = 0; n < 4; n++)
        bfr[n] = *reinterpret_cast<const long*>(lB + (wc * 64 + n * 16 + rm) * 128 + pcol);
#pragma unroll
      for (int m = 0; m < 4; m++)
#pragma unroll
        for (int n = 0; n < 4; n++)
          accf[m][n] = __builtin_amdgcn_mfma_f32_16x16x32_fp8_fp8(af[m], bfr[n], accf[m][n], 0, 0, 0);
    }
    __syncthreads();
  }

  float wgt = (ti == tj) ? 1.f : 2.f;
  float invC[4];
#pragma unroll
  for (int n = 0; n < 4; n++) invC[n] = inv[J0 + wc * 64 + n * 16 + rm];
  float psum = 0.f;
#pragma unroll
  for (int m = 0; m < 4; m++) {
#pragma unroll
    for (int r = 0; r < 4; r++) {
      float invR = inv[I0 + wr * 64 + m * 16 + kq * 4 + r];
#pragma unroll
      for (int n = 0; n < 4; n++) psum += fmaxf(accf[m][n][r] * invR * invC[n], 0.f);
    }
  }
  psum *= wgt;
  for (int off = 32; off; off >>= 1) psum += __shfl_down(psum, off, 64);
  if (lane == 0) r4[wave] = psum;
  __syncthreads();
  if (tid == 0) pgemm[bx] = r4[0] + r4[1] + r4[2] + r4[3];
}

// ---------------------------------------------------------------------------
// STAGE 4: final reduction over all partial arrays -> out[0].
// ---------------------------------------------------------------------------
__global__ __launch_bounds__(256) void finalize_kernel(const float* __restrict__ psoft,
                                                       const float* __restrict__ pcorn,
                                                       const float* __restrict__ pgemm,
                                                       float* __restrict__ out) {
  __shared__ float r4[4];
  float bce = 0.f;
  for (int i = threadIdx.x; i < 576; i += 256) bce += psoft[i];
  if (threadIdx.x < 16) bce -= pcorn[threadIdx.x];
  float g = 0.f;
  for (int i = threadIdx.x; i < 2176; i += 256) g += pgemm[i];
  float t = bce * (1.f / 2359296.f) + g * (1.f / 67108864.f);
  for (int off = 32; off; off >>= 1) t += __shfl_down(t, off, 64);
  if ((threadIdx.x & 63) == 0) r4[threadIdx.x >> 6] = t;
  __syncthreads();
  if (threadIdx.x == 0) out[0] = r4[0] + r4[1] + r4[2] + r4[3];
}

extern "C" void kernel_launch(void* const* d_in, const int* in_sizes, int n_in,
                              void* d_out, int out_size, void* d_ws, size_t ws_size,
                              hipStream_t stream) {
  (void)in_sizes; (void)n_in; (void)out_size; (void)ws_size;
  const float* desc = (const float*)d_in[0];
  const float* sd = (const float*)d_in[2];
  const float* imgs = (const float*)d_in[3];
  float* out = (float*)d_out;

  char* w = (char*)d_ws;
  float* resp = (float*)(w + OFF_RESP);
  float* cval = (float*)(w + OFF_CVAL);
  unsigned* cpos = (unsigned*)(w + OFF_CPOS);
  unsigned char* descF8 = (unsigned char*)(w + OFF_DESCB);
  float* invn = (float*)(w + OFF_INV);
  float* psoft = (float*)(w + OFF_PSOFT);
  float* pgemm = (float*)(w + OFF_PGEMM);
  float* pcorn = (float*)(w + OFF_PCORN);

  stage1_kernel<<<10496, 256, 0, stream>>>(imgs, resp, desc, descF8, invn);
  stage2_kernel<<<1152, 256, 0, stream>>>(resp, cval, cpos, (const float4*)sd, psoft);
  stage3_kernel<<<2192, 256, 0, stream>>>(cval, cpos, sd, pcorn, descF8, invn, pgemm);
  finalize_kernel<<<1, 256, 0, stream>>>(psoft, pcorn, pgemm, out);
}